// Round 1
// 212.148 us; speedup vs baseline: 1.0040x; 1.0040x over previous
//
#include <hip/hip_runtime.h>

// GridGraph adjacency (COO) for all-active 2048x2048 rook grid.
// Output layout (float32): [vals(4N) | rows(4N) | cols(4N)], direction-major
// within each: d*N + p, d in ROOK order (down, up, right, left).
//
// R8: stream-per-block restructure. dur_us=213 decomposes as ~120us harness
// re-poison fill (fixed) + ~93us kernel. Kernel was at only ~2.3 TB/s
// effective vs the 6.7 TB/s the fill demonstrates on the same buffer.
// Theory: R7's 12 interleaved write streams per block (~6000 device-wide
// fine-grained streams) destroy DRAM page locality (R6 post-mortem agrees:
// more open-page streams regressed). Now each block owns ONE of the 12
// (array,direction) streams and writes a 64 KiB contiguous chunk —
// fill-like single-stream behavior. rows/cols streams (8 of 12) need zero
// loads; vals streams read w (L3-resident) with aligned float4 + 1 scalar.

constexpr int HH = 2048;
constexpr int WW = 2048;
constexpr int NN = HH * WW;            // 4,194,304 — fits in int

__global__ __launch_bounds__(1024) void grid_adj_stream(
    const float* __restrict__ w, float* __restrict__ out)
{
    // blockIdx.x = s*256 + blk : s = stream (a*4+d), blk = chunk within stream
    const int s   = blockIdx.x >> 8;    // 0..11
    const int blk = blockIdx.x & 255;
    const int a   = s >> 2;             // 0=vals 1=rows 2=cols
    const int d   = s & 3;              // 0=down 1=up 2=right 3=left
    (void)a;

    // layout: out[(a*4 + d)*NN + p] == out[s*NN + p]
    float* __restrict__ dst = out + (long long)s * NN;

    // 4 iterations x 1024 threads x float4 = 16384 elems = 64 KiB contiguous
#pragma unroll
    for (int it = 0; it < 4; ++it) {
        const int p = ((blk << 2) + it) * 4096 + ((int)threadIdx.x << 2);
        const int j = p & (WW - 1);     // column of first of the 4 elems
        const float fp = (float)p;
        float4 r = make_float4(0.f, 0.f, 0.f, 0.f);

        if (d == 0) {                   // down (i+1, j): valid iff p < NN-WW
            if (p < NN - WW) {
                if (s == 0)      r = *(const float4*)(w + p + WW);
                else if (s == 4) r = make_float4(fp, fp + 1.f, fp + 2.f, fp + 3.f);
                else {           const float fq = fp + (float)WW;
                                 r = make_float4(fq, fq + 1.f, fq + 2.f, fq + 3.f); }
            }
        } else if (d == 1) {            // up (i-1, j): valid iff p >= WW
            if (p >= WW) {
                if (s == 1)      r = *(const float4*)(w + p - WW);
                else if (s == 5) r = make_float4(fp, fp + 1.f, fp + 2.f, fp + 3.f);
                else {           const float fq = fp - (float)WW;
                                 r = make_float4(fq, fq + 1.f, fq + 2.f, fq + 3.f); }
            }
        } else if (d == 2) {            // right (i, j+1): only k=3 at j==WW-4 invalid
            const bool lastok = (j < WW - 4);
            if (s == 2) {
                const float4 c0 = *(const float4*)(w + p);
                float w4 = 0.f;
                if (lastok) w4 = w[p + 4];          // guards OOB read at p+4==NN
                r = make_float4(c0.y, c0.z, c0.w, w4);
            } else if (s == 6) {
                r = make_float4(fp, fp + 1.f, fp + 2.f, lastok ? fp + 3.f : 0.f);
            } else {
                r = make_float4(fp + 1.f, fp + 2.f, fp + 3.f, lastok ? fp + 4.f : 0.f);
            }
        } else {                        // left (i, j-1): only k=0 at j==0 invalid
            const bool firstok = (j > 0);
            if (s == 3) {
                const float4 c0 = *(const float4*)(w + p);
                float wm1 = 0.f;
                if (firstok) wm1 = w[p - 1];        // guards OOB read at p==0
                r = make_float4(wm1, c0.x, c0.y, c0.z);
            } else if (s == 7) {
                r = make_float4(firstok ? fp : 0.f, fp + 1.f, fp + 2.f, fp + 3.f);
            } else {
                r = make_float4(firstok ? fp - 1.f : 0.f, fp, fp + 1.f, fp + 2.f);
            }
        }

        *(float4*)(dst + p) = r;
    }
}

extern "C" void kernel_launch(void* const* d_in, const int* in_sizes, int n_in,
                              void* d_out, int out_size, void* d_ws, size_t ws_size,
                              hipStream_t stream) {
    // d_in[0] = activities (all-true bool, unused), d_in[1] = vertex_weights f32 [H*W]
    const float* w = (const float*)d_in[1];
    float* out = (float*)d_out;

    const int threads = 1024;
    const int blocks  = 12 * 256;       // 12 streams x 256 chunks (64 KiB each)
    grid_adj_stream<<<blocks, threads, 0, stream>>>(w, out);
}